// Round 12
// baseline (19.170 us; speedup 1.0000x reference)
//
#include <hip/hip_runtime.h>
#include <math.h>

#define NN 4096
#define ALPHA_C 1.0f
#define H_COUP_C 0.1f
#define DT_C 0.01f
#define RPB 16  // rows per block (grid = 256 = 1 block/CU)

typedef float floatx4 __attribute__((ext_vector_type(4)));

// R10 + RPB 16 + in-loop diagonal correction (no epilogue pd gather).
//   dot_odd[i] = kd_i*v_i + wz_i*u_i
//              + H*[ sum_{j!=i} ( sin(pd[i,j])*u_j + cos(pd[i,j])*v_j ) + v_i ]
// u_j = sv[2j], v_j = sv[2j+1]:
//   j < N/2 : (u,v) = ((float2*)x_old)[j]
//   j >= N/2: (u,v) = ((float2*)y_old)[j-N/2] - ((float2*)b)[j-N/2]
// Diagonal handling: the unique (k,tid,element) that covers column i of row i
// subtracts its own sin/cos term from acc in-loop; epilogue adds v_i.
__global__ __launch_bounds__(256, 1) void cpg_fused(
        const float* __restrict__ pd,
        const float* __restrict__ x_old,
        const float* __restrict__ y_old,
        const float* __restrict__ x_old_dot,
        const float* __restrict__ omega,
        const float* __restrict__ A,
        const float* __restrict__ b,
        const float* __restrict__ h_a,
        const float* __restrict__ y_state,
        float* __restrict__ out) {
    const int tid = threadIdx.x;
    const int row0 = blockIdx.x * RPB;
    const float* __restrict__ prow = pd + (size_t)row0 * NN;

    __shared__ float lds_uv[2 * NN];        // 32 KB, slot s(j) = (j>>2)+(j&3)*1024
    __shared__ float wsum[4][RPB];

    #define NTLD4(p) __builtin_nontemporal_load(reinterpret_cast<const floatx4*>(p))

    // Phase 0: issue k=0 pd loads FIRST — latency absorbed under staging.
    floatx4 cur[RPB];
    #pragma unroll
    for (int r = 0; r < RPB; ++r)
        cur[r] = NTLD4(prow + (size_t)r * NN + tid * 4);

    // Phase A: stage uv straight from sources (each float4 = columns 2m, 2m+1)
    {
        const float4* x4 = reinterpret_cast<const float4*>(x_old);
        const float4* y4 = reinterpret_cast<const float4*>(y_old);
        const float4* b4 = reinterpret_cast<const float4*>(b);
        #pragma unroll
        for (int k = 0; k < 8; ++k) {
            int m = k * 256 + tid;              // 0..2047
            float4 t4;
            if (m < 1024) {
                t4 = x4[m];
            } else {
                float4 ya = y4[m - 1024];
                float4 bb = b4[m - 1024];
                t4 = make_float4(ya.x - bb.x, ya.y - bb.y, ya.z - bb.z, ya.w - bb.w);
            }
            int s0 = (m >> 1) + (m & 1) * 2048; // slot of j = 2m
            int s1 = s0 + 1024;                 // slot of j = 2m+1
            *reinterpret_cast<float2*>(&lds_uv[2 * s0]) = make_float2(t4.x, t4.y);
            *reinterpret_cast<float2*>(&lds_uv[2 * s1]) = make_float2(t4.z, t4.w);
        }
    }
    __syncthreads();

    // Phase B: 16 rows per block, k-outer; prefetch k+1 before computing k.
    float acc[RPB];
    #pragma unroll
    for (int r = 0; r < RPB; ++r) acc[r] = 0.f;

    #pragma unroll
    for (int k = 0; k < 4; ++k) {
        const int sbase = k * 256 + tid;    // = column_group index (jb>>2)
        floatx4 nxt[RPB];
        if (k < 3) {
            const int jn = (k + 1) * 1024 + tid * 4;
            #pragma unroll
            for (int r = 0; r < RPB; ++r)
                nxt[r] = NTLD4(prow + (size_t)r * NN + jn);
        }
        float2 uv0 = *reinterpret_cast<const float2*>(&lds_uv[2 * sbase]);
        float2 uv1 = *reinterpret_cast<const float2*>(&lds_uv[2 * (sbase + 1024)]);
        float2 uv2 = *reinterpret_cast<const float2*>(&lds_uv[2 * (sbase + 2048)]);
        float2 uv3 = *reinterpret_cast<const float2*>(&lds_uv[2 * (sbase + 3072)]);

        #pragma unroll
        for (int r = 0; r < RPB; ++r) {
            // global row i = row0 + r; its diagonal column group is
            // g = i>>2 = blockIdx*4 + (r>>2); element e = i&3 = r&3
            // (row0 is a multiple of 16). Exactly one (k,tid) has sbase==g.
            const int gdiag = blockIdx.x * (RPB / 4) + (r >> 2);
            const bool own = (sbase == gdiag);
            float a = acc[r];
            float s, c;
            s = __sinf(cur[r].x); c = __cosf(cur[r].x);
            a = fmaf(s, uv0.x, a); a = fmaf(c, uv0.y, a);
            if ((r & 3) == 0 && own) a -= s * uv0.x + c * uv0.y;
            s = __sinf(cur[r].y); c = __cosf(cur[r].y);
            a = fmaf(s, uv1.x, a); a = fmaf(c, uv1.y, a);
            if ((r & 3) == 1 && own) a -= s * uv1.x + c * uv1.y;
            s = __sinf(cur[r].z); c = __cosf(cur[r].z);
            a = fmaf(s, uv2.x, a); a = fmaf(c, uv2.y, a);
            if ((r & 3) == 2 && own) a -= s * uv2.x + c * uv2.y;
            s = __sinf(cur[r].w); c = __cosf(cur[r].w);
            a = fmaf(s, uv3.x, a); a = fmaf(c, uv3.y, a);
            if ((r & 3) == 3 && own) a -= s * uv3.x + c * uv3.y;
            acc[r] = a;
        }

        if (k < 3) {
            #pragma unroll
            for (int r = 0; r < RPB; ++r) cur[r] = nxt[r];
        }
    }
    #undef NTLD4

    // wave butterfly reduce, per row
    #pragma unroll
    for (int off = 32; off > 0; off >>= 1) {
        #pragma unroll
        for (int r = 0; r < RPB; ++r)
            acc[r] += __shfl_xor(acc[r], off, 64);
    }
    const int wid = tid >> 6;
    if ((tid & 63) == 0) {
        #pragma unroll
        for (int r = 0; r < RPB; ++r) wsum[wid][r] = acc[r];
    }
    __syncthreads();

    if (tid < RPB) {
        const int r = tid;
        const int i = row0 + r;
        float total = wsum[0][r] + wsum[1][r] + wsum[2][r] + wsum[3][r];
        int si = (i >> 2) + (i & 3) * 1024;
        float2 uvi = *reinterpret_cast<const float2*>(&lds_uv[2 * si]);
        total += uvi.y;   // diagonal contribution (pd_ii forced to 0)

        float xo = x_old[i], yo = y_old[i], bi = b[i];
        float ym = yo - bi;
        float r_sq = xo * xo + ym * ym;
        float kd = ALPHA_C * (1.0f - r_sq);
        float zeta = 1.0f - h_a[i] * (xo / (fabsf(x_old_dot[i]) + 1e-9f));
        float wz = omega[i] / zeta;
        float dot = kd * uvi.y + wz * uvi.x + H_COUP_C * total;
        float m = 2.0f * omega[i];
        dot = fminf(fmaxf(dot, -m), m);
        float y_new = y_state[i] + (dot + bi) * DT_C;
        out[i] = A[i] * y_new;
    }
}

extern "C" void kernel_launch(void* const* d_in, const int* in_sizes, int n_in,
                              void* d_out, int out_size, void* d_ws, size_t ws_size,
                              hipStream_t stream) {
    const float* x_old     = (const float*)d_in[0];
    const float* y_old     = (const float*)d_in[1];
    const float* x_old_dot = (const float*)d_in[2];
    const float* omega     = (const float*)d_in[3];
    const float* A         = (const float*)d_in[4];
    const float* b         = (const float*)d_in[5];
    const float* h_a       = (const float*)d_in[6];
    const float* pd        = (const float*)d_in[7];
    const float* y_state   = (const float*)d_in[9];
    float* out = (float*)d_out;

    cpg_fused<<<NN / RPB, 256, 0, stream>>>(pd, x_old, y_old, x_old_dot,
                                            omega, A, b, h_a, y_state, out);
}

// Round 13
// 15.663 us; speedup vs baseline: 1.2239x; 1.2239x over previous
//
#include <hip/hip_runtime.h>
#include <math.h>

#define NN 4096
#define ALPHA_C 1.0f
#define H_COUP_C 0.1f
#define DT_C 0.01f
#define RPB 8   // rows per block (grid 512; 2 blocks/CU — the TLP/amortization optimum)

typedef float floatx4 __attribute__((ext_vector_type(4)));

// FINAL (R10 revert): fused single kernel, NT pd loads, k=0 hoist,
// in-loop prefetch, RPB=8.
//   dot_odd[i] = kd_i*v_i + wz_i*u_i
//              + H*[ sum_j ( sin(pd[i,j])*u_j + cos(pd[i,j])*v_j )
//                    - (sin(pd_ii)*u_i + cos(pd_ii)*v_i) + v_i ]
// u_j = sv[2j], v_j = sv[2j+1]:
//   j < N/2 : (u,v) = ((float2*)x_old)[j]
//   j >= N/2: (u,v) = ((float2*)y_old)[j-N/2] - ((float2*)b)[j-N/2]
__global__ __launch_bounds__(256) void cpg_fused(
        const float* __restrict__ pd,
        const float* __restrict__ x_old,
        const float* __restrict__ y_old,
        const float* __restrict__ x_old_dot,
        const float* __restrict__ omega,
        const float* __restrict__ A,
        const float* __restrict__ b,
        const float* __restrict__ h_a,
        const float* __restrict__ y_state,
        float* __restrict__ out) {
    const int tid = threadIdx.x;
    const int row0 = blockIdx.x * RPB;
    const float* __restrict__ prow = pd + (size_t)row0 * NN;

    __shared__ float lds_uv[2 * NN];        // 32 KB, slot s(j) = (j>>2)+(j&3)*1024
    __shared__ float wsum[4][RPB];

    #define NTLD4(p) __builtin_nontemporal_load(reinterpret_cast<const floatx4*>(p))

    // Phase 0: issue k=0 pd loads FIRST — stream starts at cycle 0,
    // latency absorbed under staging + barrier.
    floatx4 cur[RPB];
    #pragma unroll
    for (int r = 0; r < RPB; ++r)
        cur[r] = NTLD4(prow + (size_t)r * NN + tid * 4);

    // Phase A: stage uv straight from sources (each float4 = columns 2m, 2m+1)
    {
        const float4* x4 = reinterpret_cast<const float4*>(x_old);
        const float4* y4 = reinterpret_cast<const float4*>(y_old);
        const float4* b4 = reinterpret_cast<const float4*>(b);
        #pragma unroll
        for (int k = 0; k < 8; ++k) {
            int m = k * 256 + tid;              // 0..2047
            float4 t4;
            if (m < 1024) {
                t4 = x4[m];
            } else {
                float4 ya = y4[m - 1024];
                float4 bb = b4[m - 1024];
                t4 = make_float4(ya.x - bb.x, ya.y - bb.y, ya.z - bb.z, ya.w - bb.w);
            }
            int s0 = (m >> 1) + (m & 1) * 2048; // slot of j = 2m
            int s1 = s0 + 1024;                 // slot of j = 2m+1
            *reinterpret_cast<float2*>(&lds_uv[2 * s0]) = make_float2(t4.x, t4.y);
            *reinterpret_cast<float2*>(&lds_uv[2 * s1]) = make_float2(t4.z, t4.w);
        }
    }
    __syncthreads();

    // Phase B: 8 rows per block, k-outer; prefetch k+1 before computing k.
    float acc[RPB];
    #pragma unroll
    for (int r = 0; r < RPB; ++r) acc[r] = 0.f;

    #pragma unroll
    for (int k = 0; k < 4; ++k) {
        const int sbase = k * 256 + tid;    // = jb>>2
        floatx4 nxt[RPB];
        if (k < 3) {
            const int jn = (k + 1) * 1024 + tid * 4;
            #pragma unroll
            for (int r = 0; r < RPB; ++r)
                nxt[r] = NTLD4(prow + (size_t)r * NN + jn);
        }
        float2 uv0 = *reinterpret_cast<const float2*>(&lds_uv[2 * sbase]);
        float2 uv1 = *reinterpret_cast<const float2*>(&lds_uv[2 * (sbase + 1024)]);
        float2 uv2 = *reinterpret_cast<const float2*>(&lds_uv[2 * (sbase + 2048)]);
        float2 uv3 = *reinterpret_cast<const float2*>(&lds_uv[2 * (sbase + 3072)]);

        #pragma unroll
        for (int r = 0; r < RPB; ++r) {
            float a = acc[r];
            a = fmaf(__sinf(cur[r].x), uv0.x, a);
            a = fmaf(__cosf(cur[r].x), uv0.y, a);
            a = fmaf(__sinf(cur[r].y), uv1.x, a);
            a = fmaf(__cosf(cur[r].y), uv1.y, a);
            a = fmaf(__sinf(cur[r].z), uv2.x, a);
            a = fmaf(__cosf(cur[r].z), uv2.y, a);
            a = fmaf(__sinf(cur[r].w), uv3.x, a);
            a = fmaf(__cosf(cur[r].w), uv3.y, a);
            acc[r] = a;
        }

        if (k < 3) {
            #pragma unroll
            for (int r = 0; r < RPB; ++r) cur[r] = nxt[r];
        }
    }
    #undef NTLD4

    // wave butterfly reduce, per row
    #pragma unroll
    for (int off = 32; off > 0; off >>= 1) {
        #pragma unroll
        for (int r = 0; r < RPB; ++r)
            acc[r] += __shfl_xor(acc[r], off, 64);
    }
    const int wid = tid >> 6;
    if ((tid & 63) == 0) {
        #pragma unroll
        for (int r = 0; r < RPB; ++r) wsum[wid][r] = acc[r];
    }
    __syncthreads();

    if (tid < RPB) {
        const int r = tid;
        const int i = row0 + r;
        float total = wsum[0][r] + wsum[1][r] + wsum[2][r] + wsum[3][r];
        int si = (i >> 2) + (i & 3) * 1024;
        float2 uvi = *reinterpret_cast<const float2*>(&lds_uv[2 * si]);
        // diagonal: reference forces pd_ii = 0 -> contribution v_i
        float pii = pd[(size_t)i * NN + i];
        total -= __sinf(pii) * uvi.x + __cosf(pii) * uvi.y;
        total += uvi.y;

        float xo = x_old[i], yo = y_old[i], bi = b[i];
        float ym = yo - bi;
        float r_sq = xo * xo + ym * ym;
        float kd = ALPHA_C * (1.0f - r_sq);
        float zeta = 1.0f - h_a[i] * (xo / (fabsf(x_old_dot[i]) + 1e-9f));
        float wz = omega[i] / zeta;
        float dot = kd * uvi.y + wz * uvi.x + H_COUP_C * total;
        float m = 2.0f * omega[i];
        dot = fminf(fmaxf(dot, -m), m);
        float y_new = y_state[i] + (dot + bi) * DT_C;
        out[i] = A[i] * y_new;
    }
}

extern "C" void kernel_launch(void* const* d_in, const int* in_sizes, int n_in,
                              void* d_out, int out_size, void* d_ws, size_t ws_size,
                              hipStream_t stream) {
    const float* x_old     = (const float*)d_in[0];
    const float* y_old     = (const float*)d_in[1];
    const float* x_old_dot = (const float*)d_in[2];
    const float* omega     = (const float*)d_in[3];
    const float* A         = (const float*)d_in[4];
    const float* b         = (const float*)d_in[5];
    const float* h_a       = (const float*)d_in[6];
    const float* pd        = (const float*)d_in[7];
    const float* y_state   = (const float*)d_in[9];
    float* out = (float*)d_out;

    cpg_fused<<<NN / RPB, 256, 0, stream>>>(pd, x_old, y_old, x_old_dot,
                                            omega, A, b, h_a, y_state, out);
}